// Round 5
// baseline (112.820 us; speedup 1.0000x reference)
//
#include <hip/hip_runtime.h>

#define SIZE 1024
#define MM 10
#define NTERMS 10
#define RPB 8          // batch rows resident per block
#define NTHREADS 256

typedef __attribute__((ext_vector_type(4))) _Float16 h4;   // 8B: ds_read_b64
typedef __attribute__((ext_vector_type(2))) int i2;        // same 8B as 2x u32

__device__ __forceinline__ float4 ldq(const float* p) { return *(const float4*)p; }

// acc += (float)f16(lo/hi half of r32) * w   -- single v_fma_mix_f32.
// Bitwise-identical to fmaf((float)h, w, acc): f16->f32 is exact, one fp32 fma.
#define MIX_L(acc, r32, w) \
    asm("v_fma_mix_f32 %0, %1, %2, %0 op_sel:[0,0,0] op_sel_hi:[1,0,0]" \
        : "+v"(acc) : "v"(r32), "v"(w))
#define MIX_H(acc, r32, w) \
    asm("v_fma_mix_f32 %0, %1, %2, %0 op_sel:[1,0,0] op_sel_hi:[1,0,0]" \
        : "+v"(acc) : "v"(r32), "v"(w))

// ---------------------------------------------------------------------------
// Round-4 structure EXACTLY (fp16 LDS rows, 32KB, monolithic per-term body,
// 128 VGPR, zero bank conflicts) with ONE change: every tap's
// cvt_f32_f16 + fma pair is replaced by a single v_fma_mix_f32 (inline asm,
// f16 source via op_sel) — hipcc does not pattern-match this fold, and R4's
// counters showed the cvts doubled VALU-issue (VALUBusy 29%->64%).
// All values/order identical to R4 -> absmax stays exactly 0.0625.
// ---------------------------------------------------------------------------
__global__ __launch_bounds__(NTHREADS, 2)
void butterfly_h16mix(const float* __restrict__ x,
                      const float* __restrict__ diag,
                      const float* __restrict__ subpad,
                      const float* __restrict__ suppad,
                      const float* __restrict__ logit,
                      float* __restrict__ out)
{
    __shared__ _Float16 buf[2][RPB][SIZE];   // 2*8*1024*2B = 32 KB

    const int tid = threadIdx.x;
    const int s0  = tid * 4;              // this thread's quad of s-positions
    const long rowbase = (long)blockIdx.x * RPB;

    // ---- stage this block's 8 rows into LDS (coalesced, fp32->fp16 RTN) ----
    #pragma unroll
    for (int r = 0; r < RPB; ++r) {
        const float4 v = ldq(x + (rowbase + r) * SIZE + s0);
        h4 h;
        h[0] = (_Float16)v.x; h[1] = (_Float16)v.y;
        h[2] = (_Float16)v.z; h[3] = (_Float16)v.w;
        *(h4*)&buf[0][r][s0] = h;
    }
    __syncthreads();

    int cur = 0;
    for (int t = 0; t < NTERMS; ++t) {
        const int i = NTERMS - 1 - t;     // reference applies prob[9] first

        // ---- softmax over logit[i][:] (10 values, redundant per thread) ----
        float lg[MM];
        float mx = -3.4e38f;
        #pragma unroll
        for (int j = 0; j < MM; ++j) { lg[j] = logit[i * MM + j]; mx = fmaxf(mx, lg[j]); }
        float ssum = 0.f;
        #pragma unroll
        for (int j = 0; j < MM; ++j) { lg[j] = __expf(lg[j] - mx); ssum += lg[j]; }
        const float inv = 1.0f / ssum;

        // ---- build prob-weighted coefficients for this thread's quad ----
        float D[4] = {0.f, 0.f, 0.f, 0.f};
        float Wsb[MM][4], Wsp[MM][4];
        #pragma unroll
        for (int j = 0; j < MM; ++j) {
            const float pj = lg[j] * inv;
            const float4 dg = ldq(diag   + j * SIZE + s0);
            const float4 sb = ldq(subpad + j * SIZE + s0);
            const float4 sp = ldq(suppad + j * SIZE + s0);
            D[0] = fmaf(pj, dg.x, D[0]); D[1] = fmaf(pj, dg.y, D[1]);
            D[2] = fmaf(pj, dg.z, D[2]); D[3] = fmaf(pj, dg.w, D[3]);
            Wsb[j][0] = pj * sb.x; Wsb[j][1] = pj * sb.y;
            Wsb[j][2] = pj * sb.z; Wsb[j][3] = pj * sb.w;
            Wsp[j][0] = pj * sp.x; Wsp[j][1] = pj * sp.y;
            Wsp[j][2] = pj * sp.z; Wsp[j][3] = pj * sp.w;
        }

        const bool last = (t == NTERMS - 1);

        // ---- apply the 21-diagonal operator to each resident row ----
        // OOB taps: clamp the LDS address; matching coefs are exactly 0
        // (subpad zeroed for s<d, suppad zeroed for s>=SIZE-d; clamped data
        // is finite so 0*garbage contributes +0, same as R4).
        for (int r = 0; r < RPB; ++r) {
            const _Float16* row = &buf[cur][r][0];

            const i2 xo = *(const i2*)&row[s0];
            const i2 xl = *(const i2*)&row[(s0 >= 4)         ? s0 - 4 : 0];
            const i2 xr = *(const i2*)&row[(s0 + 4 <= 1020)  ? s0 + 4 : 1020];

            // elements: [0]=x-lo, [1]=x-hi, [2]=y-lo, [3]=y-hi
            float a0 = 0.f, a1 = 0.f, a2 = 0.f, a3 = 0.f;

            // diag: a_k = D_k * xo[k]  (fma into 0 == exact product)
            MIX_L(a0, xo.x, D[0]); MIX_H(a1, xo.x, D[1]);
            MIX_L(a2, xo.y, D[2]); MIX_H(a3, xo.y, D[3]);

            // j=9, d=1  sub: xl[3], xo[0], xo[1], xo[2]
            MIX_H(a0, xl.y, Wsb[9][0]); MIX_L(a1, xo.x, Wsb[9][1]);
            MIX_H(a2, xo.x, Wsb[9][2]); MIX_L(a3, xo.y, Wsb[9][3]);
            //        sup: xo[1], xo[2], xo[3], xr[0]
            MIX_H(a0, xo.x, Wsp[9][0]); MIX_L(a1, xo.y, Wsp[9][1]);
            MIX_H(a2, xo.y, Wsp[9][2]); MIX_L(a3, xr.x, Wsp[9][3]);

            // j=8, d=2  sub: xl[2], xl[3], xo[0], xo[1]
            MIX_L(a0, xl.y, Wsb[8][0]); MIX_H(a1, xl.y, Wsb[8][1]);
            MIX_L(a2, xo.x, Wsb[8][2]); MIX_H(a3, xo.x, Wsb[8][3]);
            //        sup: xo[2], xo[3], xr[0], xr[1]
            MIX_L(a0, xo.y, Wsp[8][0]); MIX_H(a1, xo.y, Wsp[8][1]);
            MIX_L(a2, xr.x, Wsp[8][2]); MIX_H(a3, xr.x, Wsp[8][3]);

            // j=7, d=4  sub: xl[0..3]   sup: xr[0..3]
            MIX_L(a0, xl.x, Wsb[7][0]); MIX_H(a1, xl.x, Wsb[7][1]);
            MIX_L(a2, xl.y, Wsb[7][2]); MIX_H(a3, xl.y, Wsb[7][3]);
            MIX_L(a0, xr.x, Wsp[7][0]); MIX_H(a1, xr.x, Wsp[7][1]);
            MIX_L(a2, xr.y, Wsp[7][2]); MIX_H(a3, xr.y, Wsp[7][3]);

            // j=0..6, d = 512 >> j  (512,256,128,64,32,16,8)
            #pragma unroll
            for (int j = 0; j <= 6; ++j) {
                const int d = 512 >> j;
                const i2 xm = *(const i2*)&row[(s0 >= d)        ? s0 - d : 0];
                const i2 xp = *(const i2*)&row[(s0 + d <= 1020) ? s0 + d : 1020];
                MIX_L(a0, xm.x, Wsb[j][0]); MIX_H(a1, xm.x, Wsb[j][1]);
                MIX_L(a2, xm.y, Wsb[j][2]); MIX_H(a3, xm.y, Wsb[j][3]);
                MIX_L(a0, xp.x, Wsp[j][0]); MIX_H(a1, xp.x, Wsp[j][1]);
                MIX_L(a2, xp.y, Wsp[j][2]); MIX_H(a3, xp.y, Wsp[j][3]);
            }

            if (last) {
                // final term: fp32 result straight to global (coalesced b128)
                *(float4*)(out + (rowbase + r) * SIZE + s0) =
                    make_float4(a0, a1, a2, a3);
            } else {
                h4 hv;
                hv[0] = (_Float16)a0; hv[1] = (_Float16)a1;
                hv[2] = (_Float16)a2; hv[3] = (_Float16)a3;
                *(h4*)&buf[cur ^ 1][r][s0] = hv;
            }
        }
        __syncthreads();   // all writes to buf[cur^1] done before next iter reads
        cur ^= 1;
    }
}

extern "C" void kernel_launch(void* const* d_in, const int* in_sizes, int n_in,
                              void* d_out, int out_size, void* d_ws, size_t ws_size,
                              hipStream_t stream) {
    const float* x      = (const float*)d_in[0];
    const float* diag   = (const float*)d_in[1];
    const float* subpad = (const float*)d_in[2];
    const float* suppad = (const float*)d_in[3];
    const float* logit  = (const float*)d_in[4];
    float* outp = (float*)d_out;

    const int batch = in_sizes[0] / SIZE;      // 8192
    const int nblocks = batch / RPB;           // 1024

    butterfly_h16mix<<<dim3(nblocks), dim3(NTHREADS), 0, stream>>>(
        x, diag, subpad, suppad, logit, outp);
}

// Round 6
// 107.759 us; speedup vs baseline: 1.0470x; 1.0470x over previous
//
#include <hip/hip_runtime.h>

#define SIZE 1024
#define MM 10
#define NTERMS 10
#define RPB 16         // batch rows resident per block (R6: 8 -> 16)
#define NTHREADS 256

typedef __attribute__((ext_vector_type(4))) _Float16 h4;   // 8B: ds_read_b64
typedef __attribute__((ext_vector_type(2))) int i2;        // same 8B as 2x u32

__device__ __forceinline__ float4 ldq(const float* p) { return *(const float4*)p; }

// acc += (float)f16(lo/hi half of r32) * w   -- single v_fma_mix_f32.
#define MIX_L(acc, r32, w) \
    asm("v_fma_mix_f32 %0, %1, %2, %0 op_sel:[0,0,0] op_sel_hi:[1,0,0]" \
        : "+v"(acc) : "v"(r32), "v"(w))
#define MIX_H(acc, r32, w) \
    asm("v_fma_mix_f32 %0, %1, %2, %0 op_sel:[1,0,0] op_sel_hi:[1,0,0]" \
        : "+v"(acc) : "v"(r32), "v"(w))

// ---------------------------------------------------------------------------
// R5 body EXACTLY, one knob: RPB 8 -> 16 (64KB LDS, 512 blocks, 2 blocks/CU).
// Rationale: the term-invariant coef quads (diag/subpad/suppad, 480B/thread)
// are re-read from L2 every term by every block: 1024 blk -> 1.26GB of L2
// traffic (~36us pole at 34.5TB/s, invisible in FETCH_SIZE). Halving the
// block count halves that pole and amortizes coef-build VALU + softmax over
// 2x rows. Per-element FMA order unchanged -> absmax exactly 0.0625.
// ---------------------------------------------------------------------------
__global__ __launch_bounds__(NTHREADS, 2)
void butterfly_h16mix(const float* __restrict__ x,
                      const float* __restrict__ diag,
                      const float* __restrict__ subpad,
                      const float* __restrict__ suppad,
                      const float* __restrict__ logit,
                      float* __restrict__ out)
{
    __shared__ _Float16 buf[2][RPB][SIZE];   // 2*16*1024*2B = 64 KB

    const int tid = threadIdx.x;
    const int s0  = tid * 4;              // this thread's quad of s-positions
    const long rowbase = (long)blockIdx.x * RPB;

    // ---- stage this block's rows into LDS (coalesced, fp32->fp16 RTN) ----
    #pragma unroll
    for (int r = 0; r < RPB; ++r) {
        const float4 v = ldq(x + (rowbase + r) * SIZE + s0);
        h4 h;
        h[0] = (_Float16)v.x; h[1] = (_Float16)v.y;
        h[2] = (_Float16)v.z; h[3] = (_Float16)v.w;
        *(h4*)&buf[0][r][s0] = h;
    }
    __syncthreads();

    int cur = 0;
    for (int t = 0; t < NTERMS; ++t) {
        const int i = NTERMS - 1 - t;     // reference applies prob[9] first

        // ---- softmax over logit[i][:] (10 values, redundant per thread) ----
        float lg[MM];
        float mx = -3.4e38f;
        #pragma unroll
        for (int j = 0; j < MM; ++j) { lg[j] = logit[i * MM + j]; mx = fmaxf(mx, lg[j]); }
        float ssum = 0.f;
        #pragma unroll
        for (int j = 0; j < MM; ++j) { lg[j] = __expf(lg[j] - mx); ssum += lg[j]; }
        const float inv = 1.0f / ssum;

        // ---- build prob-weighted coefficients for this thread's quad ----
        float D[4] = {0.f, 0.f, 0.f, 0.f};
        float Wsb[MM][4], Wsp[MM][4];
        #pragma unroll
        for (int j = 0; j < MM; ++j) {
            const float pj = lg[j] * inv;
            const float4 dg = ldq(diag   + j * SIZE + s0);
            const float4 sb = ldq(subpad + j * SIZE + s0);
            const float4 sp = ldq(suppad + j * SIZE + s0);
            D[0] = fmaf(pj, dg.x, D[0]); D[1] = fmaf(pj, dg.y, D[1]);
            D[2] = fmaf(pj, dg.z, D[2]); D[3] = fmaf(pj, dg.w, D[3]);
            Wsb[j][0] = pj * sb.x; Wsb[j][1] = pj * sb.y;
            Wsb[j][2] = pj * sb.z; Wsb[j][3] = pj * sb.w;
            Wsp[j][0] = pj * sp.x; Wsp[j][1] = pj * sp.y;
            Wsp[j][2] = pj * sp.z; Wsp[j][3] = pj * sp.w;
        }

        const bool last = (t == NTERMS - 1);

        // ---- apply the 21-diagonal operator to each resident row ----
        // OOB taps: clamp the LDS address; matching coefs are exactly 0.
        for (int r = 0; r < RPB; ++r) {
            const _Float16* row = &buf[cur][r][0];

            const i2 xo = *(const i2*)&row[s0];
            const i2 xl = *(const i2*)&row[(s0 >= 4)         ? s0 - 4 : 0];
            const i2 xr = *(const i2*)&row[(s0 + 4 <= 1020)  ? s0 + 4 : 1020];

            float a0 = 0.f, a1 = 0.f, a2 = 0.f, a3 = 0.f;

            // diag
            MIX_L(a0, xo.x, D[0]); MIX_H(a1, xo.x, D[1]);
            MIX_L(a2, xo.y, D[2]); MIX_H(a3, xo.y, D[3]);

            // j=9, d=1
            MIX_H(a0, xl.y, Wsb[9][0]); MIX_L(a1, xo.x, Wsb[9][1]);
            MIX_H(a2, xo.x, Wsb[9][2]); MIX_L(a3, xo.y, Wsb[9][3]);
            MIX_H(a0, xo.x, Wsp[9][0]); MIX_L(a1, xo.y, Wsp[9][1]);
            MIX_H(a2, xo.y, Wsp[9][2]); MIX_L(a3, xr.x, Wsp[9][3]);

            // j=8, d=2
            MIX_L(a0, xl.y, Wsb[8][0]); MIX_H(a1, xl.y, Wsb[8][1]);
            MIX_L(a2, xo.x, Wsb[8][2]); MIX_H(a3, xo.x, Wsb[8][3]);
            MIX_L(a0, xo.y, Wsp[8][0]); MIX_H(a1, xo.y, Wsp[8][1]);
            MIX_L(a2, xr.x, Wsp[8][2]); MIX_H(a3, xr.x, Wsp[8][3]);

            // j=7, d=4
            MIX_L(a0, xl.x, Wsb[7][0]); MIX_H(a1, xl.x, Wsb[7][1]);
            MIX_L(a2, xl.y, Wsb[7][2]); MIX_H(a3, xl.y, Wsb[7][3]);
            MIX_L(a0, xr.x, Wsp[7][0]); MIX_H(a1, xr.x, Wsp[7][1]);
            MIX_L(a2, xr.y, Wsp[7][2]); MIX_H(a3, xr.y, Wsp[7][3]);

            // j=0..6, d = 512 >> j  (512,256,128,64,32,16,8)
            #pragma unroll
            for (int j = 0; j <= 6; ++j) {
                const int d = 512 >> j;
                const i2 xm = *(const i2*)&row[(s0 >= d)        ? s0 - d : 0];
                const i2 xp = *(const i2*)&row[(s0 + d <= 1020) ? s0 + d : 1020];
                MIX_L(a0, xm.x, Wsb[j][0]); MIX_H(a1, xm.x, Wsb[j][1]);
                MIX_L(a2, xm.y, Wsb[j][2]); MIX_H(a3, xm.y, Wsb[j][3]);
                MIX_L(a0, xp.x, Wsp[j][0]); MIX_H(a1, xp.x, Wsp[j][1]);
                MIX_L(a2, xp.y, Wsp[j][2]); MIX_H(a3, xp.y, Wsp[j][3]);
            }

            if (last) {
                *(float4*)(out + (rowbase + r) * SIZE + s0) =
                    make_float4(a0, a1, a2, a3);
            } else {
                h4 hv;
                hv[0] = (_Float16)a0; hv[1] = (_Float16)a1;
                hv[2] = (_Float16)a2; hv[3] = (_Float16)a3;
                *(h4*)&buf[cur ^ 1][r][s0] = hv;
            }
        }
        __syncthreads();
        cur ^= 1;
    }
}

extern "C" void kernel_launch(void* const* d_in, const int* in_sizes, int n_in,
                              void* d_out, int out_size, void* d_ws, size_t ws_size,
                              hipStream_t stream) {
    const float* x      = (const float*)d_in[0];
    const float* diag   = (const float*)d_in[1];
    const float* subpad = (const float*)d_in[2];
    const float* suppad = (const float*)d_in[3];
    const float* logit  = (const float*)d_in[4];
    float* outp = (float*)d_out;

    const int batch = in_sizes[0] / SIZE;      // 8192
    const int nblocks = batch / RPB;           // 512

    butterfly_h16mix<<<dim3(nblocks), dim3(NTHREADS), 0, stream>>>(
        x, diag, subpad, suppad, logit, outp);
}

// Round 7
// 82.110 us; speedup vs baseline: 1.3740x; 1.3124x over previous
//
#include <hip/hip_runtime.h>

#define SIZE 1024
#define MM 10
#define NTERMS 10

typedef _Float16 f16;
typedef __attribute__((ext_vector_type(8))) _Float16 f16x8;
typedef __attribute__((ext_vector_type(4))) _Float16 f16x4;
typedef __attribute__((ext_vector_type(4))) float    f32x4;
typedef __attribute__((ext_vector_type(2))) int      i2;

__device__ __forceinline__ float4 ldq(const float* p) { return *(const float4*)p; }

// fp32 FMA quad (precompute + fallback helper); a0..a3 in enclosing scope
#define FMA4F(W, v0, v1, v2, v3)                                     \
    a0 = fmaf((W)[0], (v0), a0); a1 = fmaf((W)[1], (v1), a1);        \
    a2 = fmaf((W)[2], (v2), a2); a3 = fmaf((W)[3], (v3), a3);

// ===========================================================================
// Phase 1: G = A^T where A = M_0 M_1 ... M_9  (out = x @ G).
// Apply the 10 term stencils (i = 9 first, exactly like the reference loop)
// to the 1024x1024 IDENTITY, using the R0-proven fp32 stencil body.
// G[b][s]: row b = the identity row being evolved (GEMM's k), col s (GEMM's n).
// ===========================================================================
__global__ __launch_bounds__(256, 2)
void precompute_G(const float* __restrict__ diag,
                  const float* __restrict__ subpad,
                  const float* __restrict__ suppad,
                  const float* __restrict__ logit,
                  float* __restrict__ G)
{
    __shared__ float buf[2][2][SIZE];     // 16 KB

    const int tid = threadIdx.x;
    const int s0  = tid * 4;
    const int rowbase = blockIdx.x * 2;   // 512 blocks x 2 rows = 1024

    // stage identity rows
    #pragma unroll
    for (int r = 0; r < 2; ++r) {
        float4 v;
        v.x = (rowbase + r == s0 + 0) ? 1.f : 0.f;
        v.y = (rowbase + r == s0 + 1) ? 1.f : 0.f;
        v.z = (rowbase + r == s0 + 2) ? 1.f : 0.f;
        v.w = (rowbase + r == s0 + 3) ? 1.f : 0.f;
        *(float4*)&buf[0][r][s0] = v;
    }
    __syncthreads();

    int cur = 0;
    for (int t = 0; t < NTERMS; ++t) {
        const int i = NTERMS - 1 - t;

        float lg[MM];
        float mx = -3.4e38f;
        #pragma unroll
        for (int j = 0; j < MM; ++j) { lg[j] = logit[i * MM + j]; mx = fmaxf(mx, lg[j]); }
        float ssum = 0.f;
        #pragma unroll
        for (int j = 0; j < MM; ++j) { lg[j] = __expf(lg[j] - mx); ssum += lg[j]; }
        const float inv = 1.0f / ssum;

        float D[4] = {0.f, 0.f, 0.f, 0.f};
        float Wsb[MM][4], Wsp[MM][4];
        #pragma unroll
        for (int j = 0; j < MM; ++j) {
            const float pj = lg[j] * inv;
            const float4 dg = ldq(diag   + j * SIZE + s0);
            const float4 sb = ldq(subpad + j * SIZE + s0);
            const float4 sp = ldq(suppad + j * SIZE + s0);
            D[0] = fmaf(pj, dg.x, D[0]); D[1] = fmaf(pj, dg.y, D[1]);
            D[2] = fmaf(pj, dg.z, D[2]); D[3] = fmaf(pj, dg.w, D[3]);
            Wsb[j][0] = pj * sb.x; Wsb[j][1] = pj * sb.y;
            Wsb[j][2] = pj * sb.z; Wsb[j][3] = pj * sb.w;
            Wsp[j][0] = pj * sp.x; Wsp[j][1] = pj * sp.y;
            Wsp[j][2] = pj * sp.z; Wsp[j][3] = pj * sp.w;
        }

        const bool last = (t == NTERMS - 1);
        for (int r = 0; r < 2; ++r) {
            const float* row = &buf[cur][r][0];

            const float4 xo = ldq(row + s0);
            float a0 = D[0] * xo.x, a1 = D[1] * xo.y,
                  a2 = D[2] * xo.z, a3 = D[3] * xo.w;

            const float4 xl = ldq(row + (s0 >= 4         ? s0 - 4 : 0));
            const float4 xr = ldq(row + (s0 + 4 <= 1020  ? s0 + 4 : 1020));

            FMA4F(Wsb[9], xl.w, xo.x, xo.y, xo.z)
            FMA4F(Wsp[9], xo.y, xo.z, xo.w, xr.x)
            FMA4F(Wsb[8], xl.z, xl.w, xo.x, xo.y)
            FMA4F(Wsp[8], xo.z, xo.w, xr.x, xr.y)
            FMA4F(Wsb[7], xl.x, xl.y, xl.z, xl.w)
            FMA4F(Wsp[7], xr.x, xr.y, xr.z, xr.w)
            #pragma unroll
            for (int j = 0; j <= 6; ++j) {
                const int d = 512 >> j;
                const float4 xm = ldq(row + (s0 >= d        ? s0 - d : 0));
                const float4 xp = ldq(row + (s0 + d <= 1020 ? s0 + d : 1020));
                FMA4F(Wsb[j], xm.x, xm.y, xm.z, xm.w)
                FMA4F(Wsp[j], xp.x, xp.y, xp.z, xp.w)
            }

            if (last) {
                *(float4*)(G + (long)(rowbase + r) * SIZE + s0) =
                    make_float4(a0, a1, a2, a3);
            } else {
                *(float4*)&buf[cur ^ 1][r][s0] = make_float4(a0, a1, a2, a3);
            }
        }
        __syncthreads();
        cur ^= 1;
    }
}

// ===========================================================================
// Phase 2: Gt[s][k] = (f16) G[k][s]   (LDS-tiled 64x64 transpose + cast)
// ===========================================================================
__global__ __launch_bounds__(256)
void transpose_cast(const float* __restrict__ G, f16* __restrict__ Gt)
{
    __shared__ float tile[64][65];
    const int tid = threadIdx.x;
    const int k0 = blockIdx.x * 64;
    const int s0 = blockIdx.y * 64;
    const int rr = tid >> 4;          // 0..15
    const int cc = (tid & 15) * 4;    // 0..60

    #pragma unroll
    for (int p = 0; p < 4; ++p) {
        const float4 v = ldq(G + (long)(k0 + rr + p * 16) * SIZE + s0 + cc);
        *(float4*)&tile[rr + p * 16][cc] = v;
    }
    __syncthreads();
    #pragma unroll
    for (int p = 0; p < 4; ++p) {
        const int s = rr + p * 16;
        f16x4 h;
        h[0] = (f16)tile[cc + 0][s];
        h[1] = (f16)tile[cc + 1][s];
        h[2] = (f16)tile[cc + 2][s];
        h[3] = (f16)tile[cc + 3][s];
        *(f16x4*)(Gt + (long)(s0 + s) * SIZE + k0 + cc) = h;
    }
}

// ===========================================================================
// Phase 3: out[8192,1024] = x[8192,1024(K)] @ G  via fp16 MFMA, fp32 accum.
// Tiles: BM=BN=128, BK=32; 4 waves (2x2), each wave 64x64 = 4x4 frags of
// mfma_f32_16x16x32_f16. LDS rows padded to 40 f16 (80B) -> 2-way (free)
// bank access on b128 frag reads. Double-buffered, 1 barrier/K-step,
// reg-staged (x needs fp32->fp16 cvt; T14 order: loads early, writes late).
// Frag layouts (CDNA, verified family): A lane l -> A[l&15][(l>>4)*8+e];
// B lane l -> B[(l>>4)*8+e][l&15]; D lane l,q -> D[(l>>4)*4+q][l&15].
// ===========================================================================
#define BMT 128
#define BNT 128
#define BKT 32
#define PADK 40
#define NKT (1024 / BKT)

__device__ __forceinline__ void cvt16(const float4& v0, const float4& v1, f16x8& h) {
    h[0] = (f16)v0.x; h[1] = (f16)v0.y; h[2] = (f16)v0.z; h[3] = (f16)v0.w;
    h[4] = (f16)v1.x; h[5] = (f16)v1.y; h[6] = (f16)v1.z; h[7] = (f16)v1.w;
}

__global__ __launch_bounds__(256, 2)
void gemm_f16(const float* __restrict__ x,
              const f16* __restrict__ Gt,
              float* __restrict__ out)
{
    __shared__ f16 Xs[2][BMT][PADK];   // 20 KB
    __shared__ f16 Gs[2][BNT][PADK];   // 20 KB

    const int tid  = threadIdx.x;
    const int bm   = blockIdx.x >> 3;          // 64 M-tiles
    const int bn   = blockIdx.x & 7;           // 8  N-tiles
    const int w    = tid >> 6, lane = tid & 63;
    const int wm   = w >> 1,  wn   = w & 1;
    const int lr   = lane & 15, lk = lane >> 4;

    // staging map: thread t -> row t>>1, k-half (t&1)*16
    const int sr   = tid >> 1;
    const int sh16 = (tid & 1) * 16;
    const float* xrow = x  + (long)(bm * BMT + sr) * 1024 + sh16;
    const f16*   grow = Gt + (long)(bn * BNT + sr) * 1024 + sh16;

    f32x4 acc[4][4];
    #pragma unroll
    for (int mi = 0; mi < 4; ++mi)
        #pragma unroll
        for (int ni = 0; ni < 4; ++ni)
            acc[mi][ni] = (f32x4){0.f, 0.f, 0.f, 0.f};

    // prologue: stage k-tile 0 into buffer 0
    {
        const float4 v0 = ldq(xrow), v1 = ldq(xrow + 4),
                     v2 = ldq(xrow + 8), v3 = ldq(xrow + 12);
        const f16x8 g0 = *(const f16x8*)grow;
        const f16x8 g1 = *(const f16x8*)(grow + 8);
        f16x8 h0, h1; cvt16(v0, v1, h0); cvt16(v2, v3, h1);
        *(f16x8*)&Xs[0][sr][sh16]     = h0;
        *(f16x8*)&Xs[0][sr][sh16 + 8] = h1;
        *(f16x8*)&Gs[0][sr][sh16]     = g0;
        *(f16x8*)&Gs[0][sr][sh16 + 8] = g1;
    }
    __syncthreads();

    int cur = 0;
    for (int kt = 0; kt < NKT; ++kt) {
        // issue next tile's global loads early (hide HBM under MFMA)
        float4 v0, v1, v2, v3; f16x8 g0, g1;
        const bool more = (kt + 1 < NKT);
        if (more) {
            const float* xp = xrow + (kt + 1) * BKT;
            const f16*   gp = grow + (kt + 1) * BKT;
            v0 = ldq(xp); v1 = ldq(xp + 4); v2 = ldq(xp + 8); v3 = ldq(xp + 12);
            g0 = *(const f16x8*)gp; g1 = *(const f16x8*)(gp + 8);
        }

        // compute on buf[cur]
        f16x8 a[4], b[4];
        #pragma unroll
        for (int mi = 0; mi < 4; ++mi)
            a[mi] = *(const f16x8*)&Xs[cur][wm * 64 + mi * 16 + lr][lk * 8];
        #pragma unroll
        for (int ni = 0; ni < 4; ++ni)
            b[ni] = *(const f16x8*)&Gs[cur][wn * 64 + ni * 16 + lr][lk * 8];
        #pragma unroll
        for (int mi = 0; mi < 4; ++mi)
            #pragma unroll
            for (int ni = 0; ni < 4; ++ni)
                acc[mi][ni] = __builtin_amdgcn_mfma_f32_16x16x32_f16(
                    a[mi], b[ni], acc[mi][ni], 0, 0, 0);

        // write next tile into the other buffer (vmcnt wait auto-inserted)
        if (more) {
            f16x8 h0, h1; cvt16(v0, v1, h0); cvt16(v2, v3, h1);
            *(f16x8*)&Xs[cur ^ 1][sr][sh16]     = h0;
            *(f16x8*)&Xs[cur ^ 1][sr][sh16 + 8] = h1;
            *(f16x8*)&Gs[cur ^ 1][sr][sh16]     = g0;
            *(f16x8*)&Gs[cur ^ 1][sr][sh16 + 8] = g1;
        }
        __syncthreads();
        cur ^= 1;
    }

    // epilogue: D lane l,q -> row (l>>4)*4+q, col l&15
    const long orow0 = (long)bm * BMT + wm * 64 + lk * 4;
    const int  ocol0 = bn * BNT + wn * 64 + lr;
    #pragma unroll
    for (int mi = 0; mi < 4; ++mi)
        #pragma unroll
        for (int ni = 0; ni < 4; ++ni)
            #pragma unroll
            for (int q = 0; q < 4; ++q)
                out[(orow0 + mi * 16 + q) * 1024 + ocol0 + ni * 16] = acc[mi][ni][q];
}

// ===========================================================================
// Fallback (ws too small): R6's proven stencil kernel (107.8 us).
// ===========================================================================
#define RPB 16
#define MIX_L(acc, r32, ww) \
    asm("v_fma_mix_f32 %0, %1, %2, %0 op_sel:[0,0,0] op_sel_hi:[1,0,0]" \
        : "+v"(acc) : "v"(r32), "v"(ww))
#define MIX_H(acc, r32, ww) \
    asm("v_fma_mix_f32 %0, %1, %2, %0 op_sel:[1,0,0] op_sel_hi:[1,0,0]" \
        : "+v"(acc) : "v"(r32), "v"(ww))

__global__ __launch_bounds__(256, 2)
void butterfly_h16mix(const float* __restrict__ x,
                      const float* __restrict__ diag,
                      const float* __restrict__ subpad,
                      const float* __restrict__ suppad,
                      const float* __restrict__ logit,
                      float* __restrict__ out)
{
    __shared__ f16 buf[2][RPB][SIZE];
    const int tid = threadIdx.x;
    const int s0  = tid * 4;
    const long rowbase = (long)blockIdx.x * RPB;

    #pragma unroll
    for (int r = 0; r < RPB; ++r) {
        const float4 v = ldq(x + (rowbase + r) * SIZE + s0);
        f16x4 h;
        h[0] = (f16)v.x; h[1] = (f16)v.y; h[2] = (f16)v.z; h[3] = (f16)v.w;
        *(f16x4*)&buf[0][r][s0] = h;
    }
    __syncthreads();

    int cur = 0;
    for (int t = 0; t < NTERMS; ++t) {
        const int i = NTERMS - 1 - t;
        float lg[MM];
        float mx = -3.4e38f;
        #pragma unroll
        for (int j = 0; j < MM; ++j) { lg[j] = logit[i * MM + j]; mx = fmaxf(mx, lg[j]); }
        float ssum = 0.f;
        #pragma unroll
        for (int j = 0; j < MM; ++j) { lg[j] = __expf(lg[j] - mx); ssum += lg[j]; }
        const float inv = 1.0f / ssum;

        float D[4] = {0.f, 0.f, 0.f, 0.f};
        float Wsb[MM][4], Wsp[MM][4];
        #pragma unroll
        for (int j = 0; j < MM; ++j) {
            const float pj = lg[j] * inv;
            const float4 dg = ldq(diag   + j * SIZE + s0);
            const float4 sb = ldq(subpad + j * SIZE + s0);
            const float4 sp = ldq(suppad + j * SIZE + s0);
            D[0] = fmaf(pj, dg.x, D[0]); D[1] = fmaf(pj, dg.y, D[1]);
            D[2] = fmaf(pj, dg.z, D[2]); D[3] = fmaf(pj, dg.w, D[3]);
            Wsb[j][0] = pj * sb.x; Wsb[j][1] = pj * sb.y;
            Wsb[j][2] = pj * sb.z; Wsb[j][3] = pj * sb.w;
            Wsp[j][0] = pj * sp.x; Wsp[j][1] = pj * sp.y;
            Wsp[j][2] = pj * sp.z; Wsp[j][3] = pj * sp.w;
        }

        const bool last = (t == NTERMS - 1);
        for (int r = 0; r < RPB; ++r) {
            const f16* row = &buf[cur][r][0];
            const i2 xo = *(const i2*)&row[s0];
            const i2 xl = *(const i2*)&row[(s0 >= 4)        ? s0 - 4 : 0];
            const i2 xr = *(const i2*)&row[(s0 + 4 <= 1020) ? s0 + 4 : 1020];
            float a0 = 0.f, a1 = 0.f, a2 = 0.f, a3 = 0.f;

            MIX_L(a0, xo.x, D[0]); MIX_H(a1, xo.x, D[1]);
            MIX_L(a2, xo.y, D[2]); MIX_H(a3, xo.y, D[3]);
            MIX_H(a0, xl.y, Wsb[9][0]); MIX_L(a1, xo.x, Wsb[9][1]);
            MIX_H(a2, xo.x, Wsb[9][2]); MIX_L(a3, xo.y, Wsb[9][3]);
            MIX_H(a0, xo.x, Wsp[9][0]); MIX_L(a1, xo.y, Wsp[9][1]);
            MIX_H(a2, xo.y, Wsp[9][2]); MIX_L(a3, xr.x, Wsp[9][3]);
            MIX_L(a0, xl.y, Wsb[8][0]); MIX_H(a1, xl.y, Wsb[8][1]);
            MIX_L(a2, xo.x, Wsb[8][2]); MIX_H(a3, xo.x, Wsb[8][3]);
            MIX_L(a0, xo.y, Wsp[8][0]); MIX_H(a1, xo.y, Wsp[8][1]);
            MIX_L(a2, xr.x, Wsp[8][2]); MIX_H(a3, xr.x, Wsp[8][3]);
            MIX_L(a0, xl.x, Wsb[7][0]); MIX_H(a1, xl.x, Wsb[7][1]);
            MIX_L(a2, xl.y, Wsb[7][2]); MIX_H(a3, xl.y, Wsb[7][3]);
            MIX_L(a0, xr.x, Wsp[7][0]); MIX_H(a1, xr.x, Wsp[7][1]);
            MIX_L(a2, xr.y, Wsp[7][2]); MIX_H(a3, xr.y, Wsp[7][3]);
            #pragma unroll
            for (int j = 0; j <= 6; ++j) {
                const int d = 512 >> j;
                const i2 xm = *(const i2*)&row[(s0 >= d)        ? s0 - d : 0];
                const i2 xp = *(const i2*)&row[(s0 + d <= 1020) ? s0 + d : 1020];
                MIX_L(a0, xm.x, Wsb[j][0]); MIX_H(a1, xm.x, Wsb[j][1]);
                MIX_L(a2, xm.y, Wsb[j][2]); MIX_H(a3, xm.y, Wsb[j][3]);
                MIX_L(a0, xp.x, Wsp[j][0]); MIX_H(a1, xp.x, Wsp[j][1]);
                MIX_L(a2, xp.y, Wsp[j][2]); MIX_H(a3, xp.y, Wsp[j][3]);
            }

            if (last) {
                *(float4*)(out + (rowbase + r) * SIZE + s0) =
                    make_float4(a0, a1, a2, a3);
            } else {
                f16x4 hv;
                hv[0] = (f16)a0; hv[1] = (f16)a1; hv[2] = (f16)a2; hv[3] = (f16)a3;
                *(f16x4*)&buf[cur ^ 1][r][s0] = hv;
            }
        }
        __syncthreads();
        cur ^= 1;
    }
}

extern "C" void kernel_launch(void* const* d_in, const int* in_sizes, int n_in,
                              void* d_out, int out_size, void* d_ws, size_t ws_size,
                              hipStream_t stream) {
    const float* x      = (const float*)d_in[0];
    const float* diag   = (const float*)d_in[1];
    const float* subpad = (const float*)d_in[2];
    const float* suppad = (const float*)d_in[3];
    const float* logit  = (const float*)d_in[4];
    float* outp = (float*)d_out;

    const int batch = in_sizes[0] / SIZE;          // 8192
    const size_t needG  = (size_t)SIZE * SIZE * sizeof(float);  // 4 MB
    const size_t needGt = (size_t)SIZE * SIZE * sizeof(f16);    // 2 MB

    if (d_ws != nullptr && ws_size >= needG + needGt) {
        float* G  = (float*)d_ws;
        f16*   Gt = (f16*)((char*)d_ws + needG);
        precompute_G<<<dim3(SIZE / 2), dim3(256), 0, stream>>>(
            diag, subpad, suppad, logit, G);
        transpose_cast<<<dim3(16, 16), dim3(256), 0, stream>>>(G, Gt);
        const int nblocks = (batch / BMT) * (SIZE / BNT);       // 64*8 = 512
        gemm_f16<<<dim3(nblocks), dim3(256), 0, stream>>>(x, Gt, outp);
    } else {
        butterfly_h16mix<<<dim3(batch / RPB), dim3(256), 0, stream>>>(
            x, diag, subpad, suppad, logit, outp);
    }
}